// Round 7
// baseline (594.709 us; speedup 1.0000x reference)
//
#include <hip/hip_runtime.h>

// Problem: T=8, N=256, F=128. All inputs/outputs FLOAT32 (per reference).
// Decomposition: y[t,i,j,f] = A[t,i,f] + B[t,j,f],
//   A = x @ w[:, :F]^T, B = x @ w[:, F:]^T   (per branch).
// BN train-mode stats decompose onto A/B:
//   mean = (SA+SB)/(T*N),  E[y^2] = (QA+QB)/(T*N) + 2*sum_t SA_t.SB_t/(T*N^2)
//
// R6 theory (never measured — staging bug): phase-2 should be STORE-ONLY
// vmem (LDS-fed, like the harness fill that hits 6.25 TB/s plain-store),
// with B staged once per block (8x less global B read) and denominators
// per-thread from coalesced Bt. R6 failed correctness because the B-tile
// staging copied 512 vf4 instead of 64 rows x 32 vf4 = 2048 vf4 (3/4 of
// the tile was uninitialized LDS). R7 fixes exactly that: 8 vf4 per thread.

#define TT 8
#define NN 256
#define FF 128
// rows = T*N = 2048; per-array ws region = 2048*128 = 262144 floats
// ws layout (floats):
//   A1:0  B1:262144  A2:524288  B2:786432
//   B1t:1048576  B2t:1310720          (each [8 t][128 f][256 j])
//   sums:1572864[4096] sumsq:1576960[4096] scale:1581056[256] bias:1581312[256]

typedef float vf4 __attribute__((ext_vector_type(4)));

// ---------------------------------------------------------------------------
// Kernel 1: A1,B1,A2,B2 [2048 rows][128 f] (+ transposed B1t,B2t) from x, w.
// 256 blocks x 128 threads; block = 8 rows; thread = output channel f.
// ---------------------------------------------------------------------------
__global__ __launch_bounds__(128) void k_matmul(
    const float* __restrict__ x,    // [2048][128]
    const float* __restrict__ w1,   // [128][256]
    const float* __restrict__ w2,   // [128][256]
    float* __restrict__ ws)
{
    __shared__ float xs[8][FF];
    const int tid = threadIdx.x;
    const int row0 = blockIdx.x * 8;

    {
        const float4* xv = (const float4*)(x + row0 * FF);
        ((float4*)xs)[tid]       = xv[tid];
        ((float4*)xs)[tid + 128] = xv[tid + 128];
    }
    __syncthreads();

    const int f = tid;
    float acc0[8], acc1[8], acc2[8], acc3[8];
    #pragma unroll
    for (int r = 0; r < 8; ++r) { acc0[r]=0.f; acc1[r]=0.f; acc2[r]=0.f; acc3[r]=0.f; }

    const float4* w1v = (const float4*)w1;  // row f = 64 float4 (32 A-half, 32 B-half)
    const float4* w2v = (const float4*)w2;

    #pragma unroll 4
    for (int c4 = 0; c4 < 32; ++c4) {
        float4 qa1 = w1v[f * 64 + c4];
        float4 qb1 = w1v[f * 64 + 32 + c4];
        float4 qa2 = w2v[f * 64 + c4];
        float4 qb2 = w2v[f * 64 + 32 + c4];
        const int c = c4 * 4;
        #pragma unroll
        for (int r = 0; r < 8; ++r) {
            float x0 = xs[r][c], x1 = xs[r][c + 1], x2 = xs[r][c + 2], x3 = xs[r][c + 3];
            acc0[r] = fmaf(x0, qa1.x, fmaf(x1, qa1.y, fmaf(x2, qa1.z, fmaf(x3, qa1.w, acc0[r]))));
            acc1[r] = fmaf(x0, qb1.x, fmaf(x1, qb1.y, fmaf(x2, qb1.z, fmaf(x3, qb1.w, acc1[r]))));
            acc2[r] = fmaf(x0, qa2.x, fmaf(x1, qa2.y, fmaf(x2, qa2.z, fmaf(x3, qa2.w, acc2[r]))));
            acc3[r] = fmaf(x0, qb2.x, fmaf(x1, qb2.y, fmaf(x2, qb2.z, fmaf(x3, qb2.w, acc3[r]))));
        }
    }

    float* A1 = ws;
    float* B1 = ws + 262144;
    float* A2 = ws + 524288;
    float* B2 = ws + 786432;
    #pragma unroll
    for (int r = 0; r < 8; ++r) {
        int row = row0 + r;
        A1[row * FF + f] = acc0[r];
        B1[row * FF + f] = acc1[r];
        A2[row * FF + f] = acc2[r];
        B2[row * FF + f] = acc3[r];
    }

    // transposed B copies: thread f holds B[row0..row0+7][f] in acc1/acc3
    // Bt layout per array: [t][f][256 j]; all 8 rows of a block share one t.
    {
        const int t  = row0 >> 8;
        const int n0 = row0 & 255;
        float* b1t = ws + 1048576 + (t * FF + f) * NN + n0;
        float* b2t = ws + 1310720 + (t * FF + f) * NN + n0;
        vf4 p0 = {acc1[0], acc1[1], acc1[2], acc1[3]};
        vf4 p1 = {acc1[4], acc1[5], acc1[6], acc1[7]};
        vf4 q0 = {acc3[0], acc3[1], acc3[2], acc3[3]};
        vf4 q1 = {acc3[4], acc3[5], acc3[6], acc3[7]};
        *(vf4*)(b1t)     = p0;
        *(vf4*)(b1t + 4) = p1;
        *(vf4*)(b2t)     = q0;
        *(vf4*)(b2t + 4) = q1;
    }
}

// ---------------------------------------------------------------------------
// Kernel 2a: per-(array, t) channel sums and sum-of-squares over n.
// grid = 32 (t in [0,8) x arr in [0,4)), block = 256.
// ---------------------------------------------------------------------------
__global__ __launch_bounds__(256) void k_stats(
    const float* __restrict__ ab,
    float* __restrict__ sums, float* __restrict__ sumsq)
{
    const int bx = blockIdx.x;
    const int t = bx & 7, arr = bx >> 3;
    const float* A = ab + arr * 262144 + t * NN * FF;
    const int tid = threadIdx.x;
    const int f = tid & 127, h = tid >> 7;
    float s = 0.f, q = 0.f;
    for (int n = h; n < NN; n += 2) {
        float v = A[n * FF + f];
        s += v;
        q = fmaf(v, v, q);
    }
    __shared__ float ls[256], lq[256];
    ls[tid] = s; lq[tid] = q;
    __syncthreads();
    if (tid < 128) {
        sums [(arr * 8 + t) * FF + f] = ls[tid] + ls[tid + 128];
        sumsq[(arr * 8 + t) * FF + f] = lq[tid] + lq[tid + 128];
    }
}

// ---------------------------------------------------------------------------
// Kernel 2b: fold BN (train-mode, biased var) into per-channel scale/bias.
// 1 block x 256 threads (branch = tid>>7, f = tid&127).
// ---------------------------------------------------------------------------
__global__ __launch_bounds__(256) void k_scale(
    const float* __restrict__ sums, const float* __restrict__ sumsq,
    const float* __restrict__ g1, const float* __restrict__ b1,
    const float* __restrict__ g2, const float* __restrict__ b2,
    float* __restrict__ scale, float* __restrict__ bias)
{
    const int tid = threadIdx.x;
    const int br = tid >> 7, f = tid & 127;
    const int aA = 2 * br, aB = 2 * br + 1;
    float SA = 0.f, SB = 0.f, QA = 0.f, QB = 0.f, cross = 0.f;
    #pragma unroll
    for (int t = 0; t < TT; ++t) {
        float sa = sums[(aA * 8 + t) * FF + f];
        float sb = sums[(aB * 8 + t) * FF + f];
        SA += sa; SB += sb;
        cross = fmaf(sa, sb, cross);
        QA += sumsq[(aA * 8 + t) * FF + f];
        QB += sumsq[(aB * 8 + t) * FF + f];
    }
    const float invTN  = 1.0f / 2048.0f;    // 1/(T*N)
    const float invTNN = 1.0f / 262144.0f;  // 2/(T*N*N)
    float mA = SA * invTN, mB = SB * invTN;
    float m = mA + mB;
    float ey2 = (QA + QB) * invTN + cross * invTNN;
    float var = ey2 - m * m;
    float gf = br ? g2[f] : g1[f];
    float bf = br ? b2[f] : b1[f];
    float sc = gf * rsqrtf(var + 1e-5f);
    scale[br * FF + f] = sc;
    bias [br * FF + f] = bf - m * sc;
}

// ---------------------------------------------------------------------------
// Kernel 4 (R7 = R6 with staging fix): block = (t,br) x 8-i x 64-j. 256 thr.
//   Phase 0: stage sc[128], cc[8][128] (= s*A_i+bias), Bs[64][128] (32KB =
//            2048 vf4, 8 per thread) into LDS. Coalesced float4.
//   Phase 1: denominators fully per-thread: thread (j=tid&63, ip=tid>>6)
//            owns rows (2*ip, 2*ip+1) x column j; 128 coalesced scalar Bt
//            loads; r_l[ii][j] = 1/max(l1,eps), diagonal pre-zeroed.
//   Phase 2: STORE-ONLY vmem stream: per (ii,k): 1 KB ds_read_b128, ~13
//            VALU, 1 KB plain store. No global loads in flight.
// Grid = 16 * 32 * 4 = 2048 blocks; LDS ~38.5 KB -> 4 blocks/CU.
// ---------------------------------------------------------------------------
__global__ __launch_bounds__(256) void k_edge(
    const float* __restrict__ ws,
    const float* __restrict__ scale, const float* __restrict__ bias,
    float* __restrict__ out)
{
    const int bx = blockIdx.x;            // bx = tb*128 + ig*4 + jq
    const int jq = bx & 3;
    const int ig = (bx >> 2) & 31;
    const int tb = bx >> 7;               // t*2+br
    const int br = tb & 1, t = tb >> 1;
    const int i0 = ig * 8, j0 = jq * 64;
    const int tid = threadIdx.x;

    const float* A  = ws + (2 * br) * 262144 + (t * NN + i0) * FF;      // 8 rows
    const float* B  = ws + (2 * br + 1) * 262144 + (t * NN + j0) * FF;  // 64 rows
    const float* Bt = ws + 1048576 + br * 262144 + t * FF * NN + j0;    // [128 f][256], +j0

    __shared__ float sc_l[FF];
    __shared__ float cc_l[8][FF];
    __shared__ float r_l[8][64];
    __shared__ vf4   Bs[64 * 32];         // [64 j][32 vf4] = 2048 vf4 = 32 KB

    // ---- phase 0: staging ----
    if (tid < FF) sc_l[tid] = scale[br * FF + tid];
    #pragma unroll
    for (int k = 0; k < 4; ++k) {
        int idx = k * 256 + tid;          // 0..1023 = 8 rows x 128 f
        int f = idx & 127;
        ((float*)cc_l)[idx] = fmaf(A[idx], scale[br * FF + f], bias[br * FF + f]);
    }
    {
        const vf4* Bv = (const vf4*)B;    // 64 rows x 32 vf4 = 2048 vf4
        #pragma unroll
        for (int k = 0; k < 8; ++k)       // R7 fix: all 2048, 8 per thread
            Bs[k * 256 + tid] = Bv[k * 256 + tid];
    }
    __syncthreads();

    // ---- phase 1: per-thread denominators (no cross-lane, no partials) ----
    {
        const int j  = tid & 63;
        const int ip = tid >> 6;          // i-pair: rows 2*ip, 2*ip+1
        const float* btp = Bt + j;        // Bt[f][j0+j], stride 256
        const float* c0p = cc_l[2 * ip];
        const float* c1p = cc_l[2 * ip + 1];
        float z0 = 0.f, z1 = 0.f;
        #pragma unroll 8
        for (int f = 0; f < FF; ++f) {
            float b = btp[f * NN];
            float s = sc_l[f];
            float d = b * s;
            z0 += fmaxf(d + c0p[f], 0.f);
            z1 += fmaxf(d + c1p[f], 0.f);
        }
        const int gj = j0 + j;
        r_l[2 * ip][j]     = (gj == i0 + 2 * ip)     ? 0.f : 1.0f / fmaxf(z0, 1e-12f);
        r_l[2 * ip + 1][j] = (gj == i0 + 2 * ip + 1) ? 0.f : 1.0f / fmaxf(z1, 1e-12f);
    }
    __syncthreads();

    // ---- phase 2: store-only stream ----
    const int wave = tid >> 6, lane = tid & 63;
    const int fo = (lane & 31) * 4;       // 4 channels per lane
    const int jh = lane >> 5;             // row of the pair

    const vf4 s4 = *(const vf4*)(sc_l + fo);
    float* outb = out + ((size_t)(tb * NN + i0) * NN + j0) * FF;

    for (int ii = 0; ii < 8; ++ii) {
        const vf4 c4 = *(const vf4*)(&cc_l[ii][fo]);
        float* orow = outb + (size_t)ii * NN * FF;
        #pragma unroll 8
        for (int k = 0; k < 8; ++k) {
            const int jr = wave * 16 + k * 2 + jh;   // 0..63
            vf4 b = Bs[jr * 32 + (lane & 31)];
            float rv = r_l[ii][jr];
            vf4 v;
            v.x = fmaxf(fmaf(b.x, s4.x, c4.x), 0.f) * rv;
            v.y = fmaxf(fmaf(b.y, s4.y, c4.y), 0.f) * rv;
            v.z = fmaxf(fmaf(b.z, s4.z, c4.z), 0.f) * rv;
            v.w = fmaxf(fmaf(b.w, s4.w, c4.w), 0.f) * rv;
            *(vf4*)(orow + (size_t)jr * FF + fo) = v;   // plain store
        }
    }
}

// ---------------------------------------------------------------------------
extern "C" void kernel_launch(void* const* d_in, const int* in_sizes, int n_in,
                              void* d_out, int out_size, void* d_ws, size_t ws_size,
                              hipStream_t stream)
{
    const float* x  = (const float*)d_in[0];   // node_feats f32 [8,256,128]
    const float* w1 = (const float*)d_in[1];   // w1 f32 [128,256]
    const float* g1 = (const float*)d_in[2];
    const float* b1 = (const float*)d_in[3];
    const float* w2 = (const float*)d_in[4];
    const float* g2 = (const float*)d_in[5];
    const float* b2 = (const float*)d_in[6];

    float* ws    = (float*)d_ws;            // A1,B1,A2,B2 + B1t,B2t
    float* sums  = ws + 1572864;            // [4][8][128]
    float* sumsq = sums + 4096;             // [4][8][128]
    float* scale = sumsq + 4096;            // [2][128]
    float* bias  = scale + 256;             // [2][128]
    float* out = (float*)d_out;

    k_matmul<<<256, 128, 0, stream>>>(x, w1, w2, ws);
    k_stats <<<32, 256, 0, stream>>>(ws, sums, sumsq);
    k_scale <<<1, 256, 0, stream>>>(sums, sumsq, g1, b1, g2, b2, scale, bias);
    k_edge  <<<2048, 256, 0, stream>>>(ws, scale, bias, out);
}